// Round 6
// baseline (21379.857 us; speedup 1.0000x reference)
//
#include <hip/hip_runtime.h>
#include <math.h>

// Sizes: B=32, S=256, T=256, V=10000, E=512, H=1024, C=1024, SE=8
// in1 = E+SE+C = 1544, 3H = 3072, M = B*T = 8192 (row r = t*32 + b)
#define NBLK 256

__device__ __forceinline__ float sigf(float x) { return 1.0f / (1.0f + __expf(-x)); }

// ---------------- prep: gather ctx/style, build concat vectors, zero bT slot 0 --------------
__global__ void prep_kernel(const float* __restrict__ enc_output,
                            const int*   __restrict__ enc_len,
                            const int*   __restrict__ styles,
                            const float* __restrict__ style_table,
                            float* __restrict__ xA,     // [32][1032] = [ctx, style]
                            float* __restrict__ xB,     // [32][1032] = [style, ctx]
                            float* __restrict__ bT0)    // [256][32][4] zeros (b_state[0], packed)
{
    int b = blockIdx.x;
    int tid = threadIdx.x;
    int last = enc_len[b] - 1;
    last = last < 0 ? 0 : (last > 255 ? 255 : last);
    const float* ctx = enc_output + ((size_t)b * 256 + last) * 1024;
    for (int k = tid; k < 1024; k += blockDim.x) {
        float v = ctx[k];
        xA[b * 1032 + k]     = v;
        xB[b * 1032 + 8 + k] = v;
        bT0[b * 1024 + k]    = 0.0f;   // 32 blocks x 1024 = 32768 floats
    }
    if (tid < 8) {
        float se = style_table[styles[b] * 8 + tid];
        xA[b * 1032 + 1024 + tid] = se;
        xB[b * 1032 + tid]        = se;
    }
}

// ---------------- generic fp32 GEMM: C[M,N] = A[M,K] * W^T (+bias +rowbase) ----------------
// BMODE 0: W is [N][ldb]; BMODE 1: W is [K][ldb=N]
// EPI 0: C[r*N+n]; EPI 1: out[(b*256+t)*N+n]; EPI 2: out[(r>>5)*N*32 + n*32 + (r&31)]
// EPI 3: packed-transposed state out[(n>>2)*128 + (r&31)*4 + (n&3)]  (M<=32)
// GATHER 1: A row r = emb_table[dec_in[(r&31)*256 + (r>>5)]]
template<int BMODE, int EPI, int GATHER>
__global__ __launch_bounds__(256, 2)
void gemm128(const float* __restrict__ A, int lda,
             const float* __restrict__ W, int ldb,
             const float* __restrict__ bias,
             const float* __restrict__ rowbase,
             const int*   __restrict__ gidx,
             float* __restrict__ Cout,
             int M, int N, int K)
{
    __shared__ float As[8][132];
    __shared__ float Bs[8][132];
    const int tid = threadIdx.x;
    const int r0 = blockIdx.x * 128;
    const int n0 = blockIdx.y * 128;
    const int tx = tid & 15;
    const int ty = tid >> 4;

    float acc[8][8];
#pragma unroll
    for (int i = 0; i < 8; ++i)
#pragma unroll
        for (int j = 0; j < 8; ++j) acc[i][j] = 0.0f;

    const int am  = tid >> 1;
    const int akq = (tid & 1) * 4;
    const bool avalid = (r0 + am) < M;
    const float* arow;
    {
        int r = r0 + am; if (r >= M) r = M - 1;
        if (GATHER) {
            int idx = gidx[(r & 31) * 256 + (r >> 5)];
            arow = A + (size_t)idx * lda;
        } else {
            arow = A + (size_t)r * lda;
        }
    }

    for (int k0 = 0; k0 < K; k0 += 8) {
        float4 av = make_float4(0.f, 0.f, 0.f, 0.f);
        if (avalid) av = *(const float4*)(arow + k0 + akq);

        if (BMODE == 0) {
            const int ncol = tid >> 1;
            const int kq   = (tid & 1) * 4;
            float4 bv = make_float4(0.f, 0.f, 0.f, 0.f);
            int j = n0 + ncol;
            if (j < N) bv = *(const float4*)(W + (size_t)j * ldb + k0 + kq);
            __syncthreads();
            As[akq + 0][am] = av.x; As[akq + 1][am] = av.y;
            As[akq + 2][am] = av.z; As[akq + 3][am] = av.w;
            Bs[kq + 0][ncol] = bv.x; Bs[kq + 1][ncol] = bv.y;
            Bs[kq + 2][ncol] = bv.z; Bs[kq + 3][ncol] = bv.w;
        } else {
            const int kk = tid >> 5;
            const int nq = (tid & 31) * 4;
            float4 bv = make_float4(0.f, 0.f, 0.f, 0.f);
            int j = n0 + nq;
            if (j < N) bv = *(const float4*)(W + (size_t)(k0 + kk) * ldb + j);
            __syncthreads();
            As[akq + 0][am] = av.x; As[akq + 1][am] = av.y;
            As[akq + 2][am] = av.z; As[akq + 3][am] = av.w;
            *(float4*)&Bs[kk][nq] = bv;
        }
        __syncthreads();

#pragma unroll
        for (int kk = 0; kk < 8; ++kk) {
            float4 a0 = *(const float4*)&As[kk][ty * 8];
            float4 a1 = *(const float4*)&As[kk][ty * 8 + 4];
            float4 b0 = *(const float4*)&Bs[kk][tx * 8];
            float4 b1 = *(const float4*)&Bs[kk][tx * 8 + 4];
            float ar[8] = {a0.x, a0.y, a0.z, a0.w, a1.x, a1.y, a1.z, a1.w};
            float br[8] = {b0.x, b0.y, b0.z, b0.w, b1.x, b1.y, b1.z, b1.w};
#pragma unroll
            for (int i = 0; i < 8; ++i)
#pragma unroll
                for (int j = 0; j < 8; ++j)
                    acc[i][j] = fmaf(ar[i], br[j], acc[i][j]);
        }
    }

#pragma unroll
    for (int i = 0; i < 8; ++i) {
        int r = r0 + ty * 8 + i;
        if (r >= M) continue;
        const float* rb = rowbase ? (rowbase + (size_t)(r & 31) * N) : nullptr;
#pragma unroll
        for (int jq = 0; jq < 2; ++jq) {
            int n = n0 + tx * 8 + jq * 4;
            if (n >= N) continue;
            float4 v;
            v.x = acc[i][jq * 4 + 0]; v.y = acc[i][jq * 4 + 1];
            v.z = acc[i][jq * 4 + 2]; v.w = acc[i][jq * 4 + 3];
            if (bias) {
                float4 bz = *(const float4*)(bias + n);
                v.x += bz.x; v.y += bz.y; v.z += bz.z; v.w += bz.w;
            }
            if (rb) {
                float4 rz = *(const float4*)(rb + n);
                v.x += rz.x; v.y += rz.y; v.z += rz.z; v.w += rz.w;
            }
            if (EPI == 2) {
                size_t basei = (size_t)(r >> 5) * (size_t)N * 32 + (size_t)(r & 31);
                Cout[basei + (size_t)(n + 0) * 32] = v.x;
                Cout[basei + (size_t)(n + 1) * 32] = v.y;
                Cout[basei + (size_t)(n + 2) * 32] = v.z;
                Cout[basei + (size_t)(n + 3) * 32] = v.w;
            } else if (EPI == 3) {
                *(float4*)(Cout + (size_t)(n >> 2) * 128 + (size_t)(r & 31) * 4) = v;
            } else {
                float* crow = (EPI == 0) ? (Cout + (size_t)r * N)
                                         : (Cout + (size_t)((r & 31) * 256 + (r >> 5)) * (size_t)N);
                *(float4*)(crow + n) = v;
            }
        }
    }
}

// ---------------- manual grid barrier (graph-capturable) ----------------
__device__ __forceinline__ void grid_sync(int* cnt, int* gen) {
    __syncthreads();
    if (threadIdx.x == 0) {
        __threadfence();   // release: make prior writes visible device-wide
        int g = __hip_atomic_load(gen, __ATOMIC_RELAXED, __HIP_MEMORY_SCOPE_AGENT);
        int prev = __hip_atomic_fetch_add(cnt, 1, __ATOMIC_ACQ_REL, __HIP_MEMORY_SCOPE_AGENT);
        if (prev == NBLK - 1) {
            __hip_atomic_store(cnt, 0, __ATOMIC_RELAXED, __HIP_MEMORY_SCOPE_AGENT);
            __hip_atomic_fetch_add(gen, 1, __ATOMIC_RELEASE, __HIP_MEMORY_SCOPE_AGENT);
        } else {
            long long spins = 0;
            while (__hip_atomic_load(gen, __ATOMIC_ACQUIRE, __HIP_MEMORY_SCOPE_AGENT) == g) {
                __builtin_amdgcn_s_sleep(2);
                if (++spins > (1LL << 22)) break;   // safety bail (visible failure, not hang)
            }
        }
        __threadfence();   // acquire: invalidate caches before next iter's reads
    }
    __syncthreads();
}

// ---------------- persistent scan, LDS weights, broadcast reads, regular launch -------------
// 256 blocks x 512 threads (1 block/CU via 157.8KB LDS). Block bk owns u in {4bk..4bk+3}.
// Thread: b = tid&31 (lane), kk = (tid>>5)&1, ks = tid>>6 (wave). k-slice = ks*128 + kk*64.
// State layout (packed transposed): h[(u>>2)][b][u&3]; ring of 2 slots for aT and bT.
// Weight LDS: wlds[(ul*9+v)*1024 + k] — all 64 lanes of a wave read the same float4 (kk gives
// 2 distinct addrs, 64 floats apart = same bank group = 2-way = free).
__global__ __launch_bounds__(512, 2)
void scan_persistent(const float* __restrict__ gi1T,  // [256][3072][32]
                     float* __restrict__ aT,           // [2][256][32][4]
                     float* __restrict__ bT,           // [2][256][32][4]
                     float* __restrict__ bSeq,         // [257][32][1024] (slots 1..256 written)
                     float* __restrict__ gbuf,         // [2][3072][32]
                     const float* __restrict__ Whh1, const float* __restrict__ bhh1,
                     const float* __restrict__ Wih2, const float* __restrict__ bih2,
                     const float* __restrict__ Whh2, const float* __restrict__ bhh2,
                     int* __restrict__ barCnt, int* __restrict__ barGen)
{
    __shared__ float wlds[36864];      // 144 KB
    __shared__ float part[8][9][32];   // 9.2 KB
    __shared__ float gsum[9][32];      // 1.2 KB

    const int tid = threadIdx.x;
    const int b   = tid & 31;
    const int kk  = (tid >> 5) & 1;
    const int ks  = tid >> 6;
    const int bk  = blockIdx.x;
    const int koff = ks * 128 + kk * 64;
    const int role = tid >> 5;         // writers: tid<96 -> roles 0(L1),1(G2),2(L2)

    // ---- stage weights once: v0-2 Whh1, v3-5 Wih2, v6-8 Whh2, for u = 4bk+ul ----
    for (int c = tid; c < 9216; c += 512) {     // c = float4 index
        int k4 = c & 255;
        int uv = c >> 8;                        // 0..35
        int ul = uv / 9, v = uv - ul * 9;
        int u  = bk * 4 + ul;
        const float* W = (v < 3) ? Whh1 : (v < 6 ? Wih2 : Whh2);
        int g = v % 3;
        float4 w = *(const float4*)(W + ((size_t)(g * 1024 + u)) * 1024 + k4 * 4);
        *(float4*)&wlds[(size_t)uv * 1024 + k4 * 4] = w;
    }

    // per-writer bias constants
    float wb[3][4];
    if (tid < 96) {
        const float* bias = (role == 0) ? bhh1 : (role == 1 ? bih2 : bhh2);
#pragma unroll
        for (int g = 0; g < 3; ++g)
#pragma unroll
            for (int ul = 0; ul < 4; ++ul)
                wb[g][ul] = bias[g * 1024 + bk * 4 + ul];
    }
    __syncthreads();

    float aOut[4] = {0, 0, 0, 0};
    float bOut[4] = {0, 0, 0, 0};

    for (int s = 0; s <= 257; ++s) {
        const bool doL1 = (s <= 255);
        const bool doG2 = (s >= 1 && s <= 256);
        const bool doL2 = (s >= 2);
        const bool doA  = doL1 || doG2;
        const int slot  = s & 1;

        // ---- writer-role prefetch (gate inputs + previous h), hidden under compute ----
        float pgi[3][4];
        float4 hprev = make_float4(0.f, 0.f, 0.f, 0.f);
        if (role == 0 && doL1) {
            const float* gi = gi1T + (size_t)s * 98304;
#pragma unroll
            for (int g = 0; g < 3; ++g)
#pragma unroll
                for (int ul = 0; ul < 4; ++ul)
                    pgi[g][ul] = gi[(g * 1024 + bk * 4 + ul) * 32 + b];
            hprev = *((const float4*)aT + (size_t)slot * 8192 + bk * 32 + b);
        } else if (role == 2 && doL2) {
            const float* g2 = gbuf + (size_t)((s + 1) & 1) * 98304;
#pragma unroll
            for (int g = 0; g < 3; ++g)
#pragma unroll
                for (int ul = 0; ul < 4; ++ul)
                    pgi[g][ul] = g2[(g * 1024 + bk * 4 + ul) * 32 + b];
            hprev = *((const float4*)bT + (size_t)slot * 8192 + bk * 32 + b);
        }

        float accA[6][4], accC[3][4];
#pragma unroll
        for (int v = 0; v < 6; ++v)
#pragma unroll
            for (int ul = 0; ul < 4; ++ul) accA[v][ul] = 0.f;
#pragma unroll
        for (int v = 0; v < 3; ++v)
#pragma unroll
            for (int ul = 0; ul < 4; ++ul) accC[v][ul] = 0.f;

        // ---- A-phase: h_a[s] against Whh1 (v0-2) and Wih2 (v3-5) ----
        if (doA) {
            float4 hA[16];
            const float4* src = (const float4*)aT + (size_t)slot * 8192 + b;
#pragma unroll
            for (int i = 0; i < 16; ++i) hA[i] = src[(ks * 32 + kk * 16 + i) * 32];
#pragma unroll
            for (int ul = 0; ul < 4; ++ul)
#pragma unroll
                for (int v = 0; v < 6; ++v) {
                    const float4* w = (const float4*)&wlds[(ul * 9 + v) * 1024 + koff];
                    float s0 = 0.f, s1 = 0.f, s2 = 0.f, s3 = 0.f;
#pragma unroll
                    for (int i = 0; i < 16; ++i) {
                        float4 wv = w[i];
                        s0 = fmaf(hA[i].x, wv.x, s0);
                        s1 = fmaf(hA[i].y, wv.y, s1);
                        s2 = fmaf(hA[i].z, wv.z, s2);
                        s3 = fmaf(hA[i].w, wv.w, s3);
                    }
                    accA[v][ul] = (s0 + s1) + (s2 + s3);
                }
        }
        // ---- C-phase: h_b[s-2] against Whh2 (v6-8) ----
        if (doL2) {
            float4 hB[16];
            const float4* src = (const float4*)bT + (size_t)slot * 8192 + b;
#pragma unroll
            for (int i = 0; i < 16; ++i) hB[i] = src[(ks * 32 + kk * 16 + i) * 32];
#pragma unroll
            for (int ul = 0; ul < 4; ++ul)
#pragma unroll
                for (int v = 0; v < 3; ++v) {
                    const float4* w = (const float4*)&wlds[(ul * 9 + 6 + v) * 1024 + koff];
                    float s0 = 0.f, s1 = 0.f, s2 = 0.f, s3 = 0.f;
#pragma unroll
                    for (int i = 0; i < 16; ++i) {
                        float4 wv = w[i];
                        s0 = fmaf(hB[i].x, wv.x, s0);
                        s1 = fmaf(hB[i].y, wv.y, s1);
                        s2 = fmaf(hB[i].z, wv.z, s2);
                        s3 = fmaf(hB[i].w, wv.w, s3);
                    }
                    accC[v][ul] = (s0 + s1) + (s2 + s3);
                }
        }

        // ---- fold kk (lane bit 5) ----
#pragma unroll
        for (int v = 0; v < 6; ++v)
#pragma unroll
            for (int ul = 0; ul < 4; ++ul)
                accA[v][ul] += __shfl_xor(accA[v][ul], 32);
#pragma unroll
        for (int v = 0; v < 3; ++v)
#pragma unroll
            for (int ul = 0; ul < 4; ++ul)
                accC[v][ul] += __shfl_xor(accC[v][ul], 32);

        // ---- per-u rounds: cross-wave reduce + gates ----
#pragma unroll
        for (int ul = 0; ul < 4; ++ul) {
            if (kk == 0) {
#pragma unroll
                for (int v = 0; v < 6; ++v) part[ks][v][b] = accA[v][ul];
#pragma unroll
                for (int v = 0; v < 3; ++v) part[ks][6 + v][b] = accC[v][ul];
            }
            __syncthreads();
            if (tid < 288) {
                int v = tid >> 5, bb = tid & 31;
                float s8 = 0.f;
#pragma unroll
                for (int r = 0; r < 8; ++r) s8 += part[r][v][bb];
                gsum[v][bb] = s8;
            }
            __syncthreads();
            if (tid < 96) {
                const int u = bk * 4 + ul;
                if (role == 0) {
                    if (doL1) {
                        float r = sigf(pgi[0][ul] + gsum[0][b] + wb[0][ul]);
                        float z = sigf(pgi[1][ul] + gsum[1][b] + wb[1][ul]);
                        float n = tanhf(pgi[2][ul] + r * (gsum[2][b] + wb[2][ul]));
                        float hp = (ul == 0) ? hprev.x : (ul == 1) ? hprev.y : (ul == 2) ? hprev.z : hprev.w;
                        aOut[ul] = (1.0f - z) * n + z * hp;
                    }
                } else if (role == 1) {
                    if (doG2) {
                        float* g2 = gbuf + (size_t)(s & 1) * 98304;
#pragma unroll
                        for (int g = 0; g < 3; ++g)
                            g2[(g * 1024 + u) * 32 + b] = gsum[3 + g][b] + wb[g][ul];
                    }
                } else {
                    if (doL2) {
                        float r = sigf(pgi[0][ul] + gsum[6][b] + wb[0][ul]);
                        float z = sigf(pgi[1][ul] + gsum[7][b] + wb[1][ul]);
                        float n = tanhf(pgi[2][ul] + r * (gsum[8][b] + wb[2][ul]));
                        float hp = (ul == 0) ? hprev.x : (ul == 1) ? hprev.y : (ul == 2) ? hprev.z : hprev.w;
                        bOut[ul] = (1.0f - z) * n + z * hp;
                    }
                }
            }
        }

        // ---- state writes (packed transposed float4; plus bSeq normal layout) ----
        if (role == 0 && doL1) {
            float4 o = make_float4(aOut[0], aOut[1], aOut[2], aOut[3]);
            *((float4*)aT + (size_t)((s + 1) & 1) * 8192 + bk * 32 + b) = o;
        }
        if (role == 2 && doL2) {
            float4 o = make_float4(bOut[0], bOut[1], bOut[2], bOut[3]);
            *((float4*)bT + (size_t)((s + 1) & 1) * 8192 + bk * 32 + b) = o;
            *(float4*)(bSeq + (size_t)(s - 1) * 32768 + (size_t)b * 1024 + bk * 4) = o;
        }

        grid_sync(barCnt, barGen);
    }
}

// ---------------- fused log-softmax tail: lse, gather log-prob, argmax ----------------
__global__ __launch_bounds__(256)
void softmax_tail(const float* __restrict__ logits,  // [(b*256+t)][10000]
                  const int*   __restrict__ dec_out,
                  float* __restrict__ lp,
                  float* __restrict__ pred)
{
    const int p = blockIdx.x;
    const int tid = threadIdx.x;
    const float* row = logits + (size_t)p * 10000;

    float m = -INFINITY, s = 0.0f;
    int am = 0;
    for (int q = tid; q < 2500; q += 256) {
        float4 v = *(const float4*)(row + q * 4);
        float xs[4] = {v.x, v.y, v.z, v.w};
#pragma unroll
        for (int c = 0; c < 4; ++c) {
            float x = xs[c];
            if (x > m) {
                s = s * __expf(m - x) + 1.0f;
                m = x;
                am = q * 4 + c;
            } else {
                s += __expf(x - m);
            }
        }
    }
    __shared__ float sm[256];
    __shared__ float ss[256];
    __shared__ int   sa[256];
    sm[tid] = m; ss[tid] = s; sa[tid] = am;
    __syncthreads();
    for (int w = 128; w > 0; w >>= 1) {
        if (tid < w) {
            float m1 = sm[tid],     s1 = ss[tid];     int a1 = sa[tid];
            float m2 = sm[tid + w], s2 = ss[tid + w]; int a2 = sa[tid + w];
            float M2 = fmaxf(m1, m2);
            float S2 = s1 * __expf(m1 - M2) + s2 * __expf(m2 - M2);
            int A2;
            if (m1 > m2) A2 = a1;
            else if (m2 > m1) A2 = a2;
            else A2 = (a1 < a2) ? a1 : a2;
            sm[tid] = M2; ss[tid] = S2; sa[tid] = A2;
        }
        __syncthreads();
    }
    if (tid == 0) {
        float lse = sm[0] + logf(ss[0]);
        int tok = dec_out[p];
        lp[p]   = row[tok] - lse;
        pred[p] = (float)sa[0];
    }
}

extern "C" void kernel_launch(void* const* d_in, const int* in_sizes, int n_in,
                              void* d_out, int out_size, void* d_ws, size_t ws_size,
                              hipStream_t stream)
{
    const float* enc_output  = (const float*)d_in[0];
    const int*   enc_len     = (const int*)  d_in[1];
    const int*   styles      = (const int*)  d_in[2];
    const int*   dec_in      = (const int*)  d_in[3];
    const int*   dec_out     = (const int*)  d_in[4];
    const float* emb_table   = (const float*)d_in[5];
    const float* style_table = (const float*)d_in[6];
    const float* Wp   = (const float*)d_in[7];
    const float* bp   = (const float*)d_in[8];
    const float* Wih1 = (const float*)d_in[9];
    const float* Whh1 = (const float*)d_in[10];
    const float* bih1 = (const float*)d_in[11];
    const float* bhh1 = (const float*)d_in[12];
    const float* Wih2 = (const float*)d_in[13];
    const float* Whh2 = (const float*)d_in[14];
    const float* bih2 = (const float*)d_in[15];
    const float* bhh2 = (const float*)d_in[16];
    const float* Wout = (const float*)d_in[17];
    const float* bout = (const float*)d_in[18];

    float* out = (float*)d_out;

    // Scratch inside the logits region of d_out (all dead before logits GEMM overwrites):
    float* gi1T  = out;                  // [256][3072][32]   = 25,165,824 f
    float* aT    = out + 25165824;       // [2][256][32][4]   =     65,536 f
    float* bTr   = out + 25231360;       // [2][256][32][4]   =     65,536 f
    float* base1 = out + 25296896;       // [32][3072]        =     98,304 f
    float* xA    = out + 25395200;       // [32][1032]
    float* xB    = out + 25428224;       // [32][1032]
    float* gbuf  = out + 25461248;       // [2][3072][32]     =    196,608 f
    int*   barP  = (int*)(out + 25657856); // 2 ints (+pad)   (ends far below 81,920,000)
    // b_seq (normal layout, feeds logits GEMM) survives into the GEMM -> d_ws:
    float* bSeq  = (float*)d_ws;         // [257][32][1024] = 33.7 MB

    float* logitsOut = out;              // [32][256][10000]
    float* lpOut     = out + 81920000;   // [32][256]
    float* predOut   = out + 81928192;   // [32][256]

    // Phase 0: gather + concat vectors + zero bT slot 0
    prep_kernel<<<32, 256, 0, stream>>>(enc_output, enc_len, styles, style_table, xA, xB, bTr);

    // h0 = xA @ Wp^T + bp -> aT slot 0 (packed transposed via EPI 3)
    gemm128<0, 3, 0><<<dim3(1, 8), 256, 0, stream>>>(xA, 1032, Wp, 1032, bp, nullptr, nullptr,
                                                     aT, 32, 1024, 1032);
    // base1 = xB @ Wih1[:, 512:]^T + bih1
    gemm128<0, 0, 0><<<dim3(1, 24), 256, 0, stream>>>(xB, 1032, Wih1 + 512, 1544, bih1, nullptr, nullptr,
                                                      base1, 32, 3072, 1032);
    // gi1T[t][col][b] = (emb[dec_in] @ Wih1[:, :512]^T + base1[b]) transposed per t
    gemm128<0, 2, 1><<<dim3(64, 24), 256, 0, stream>>>(emb_table, 512, Wih1, 1544, nullptr, base1, dec_in,
                                                       gi1T, 8192, 3072, 512);

    // barrier counters must start at 0 every call (ws/out are poisoned, not re-zeroed)
    hipMemsetAsync(barP, 0, 256, stream);

    // Persistent pipelined scan: regular launch (graph-capturable), manual grid barrier
    scan_persistent<<<NBLK, 512, 0, stream>>>(gi1T, aT, bTr, bSeq, gbuf,
                                              Whh1, bhh1, Wih2, bih2, Whh2, bhh2,
                                              barP, barP + 1);

    // logits = b_seq[1..256] @ Wout + bout, written in [b][t][v] order
    gemm128<1, 1, 0><<<dim3(64, 79), 256, 0, stream>>>(bSeq + 32768, 1024, Wout, 10000, bout, nullptr, nullptr,
                                                       logitsOut, 8192, 10000, 1024);
    // log-softmax gather + argmax
    softmax_tail<<<8192, 256, 0, stream>>>(logitsOut, dec_out, lpOut, predOut);
}

// Round 7
// 14860.097 us; speedup vs baseline: 1.4387x; 1.4387x over previous
//
#include <hip/hip_runtime.h>
#include <math.h>

// Sizes: B=32, S=256, T=256, V=10000, E=512, H=1024, C=1024, SE=8
// in1 = E+SE+C = 1544, 3H = 3072, M = B*T = 8192 (row r = t*32 + b)
#define NBLK 256

__device__ __forceinline__ float sigf(float x) { return 1.0f / (1.0f + __expf(-x)); }

// ---------------- prep: gather ctx/style, build concat vectors, zero bT slot 0 --------------
__global__ void prep_kernel(const float* __restrict__ enc_output,
                            const int*   __restrict__ enc_len,
                            const int*   __restrict__ styles,
                            const float* __restrict__ style_table,
                            float* __restrict__ xA,     // [32][1032] = [ctx, style]
                            float* __restrict__ xB,     // [32][1032] = [style, ctx]
                            float* __restrict__ bT0)    // [256][32][4] zeros (b_state[0], packed)
{
    int b = blockIdx.x;
    int tid = threadIdx.x;
    int last = enc_len[b] - 1;
    last = last < 0 ? 0 : (last > 255 ? 255 : last);
    const float* ctx = enc_output + ((size_t)b * 256 + last) * 1024;
    for (int k = tid; k < 1024; k += blockDim.x) {
        float v = ctx[k];
        xA[b * 1032 + k]     = v;
        xB[b * 1032 + 8 + k] = v;
        bT0[b * 1024 + k]    = 0.0f;   // 32 blocks x 1024 = 32768 floats
    }
    if (tid < 8) {
        float se = style_table[styles[b] * 8 + tid];
        xA[b * 1032 + 1024 + tid] = se;
        xB[b * 1032 + tid]        = se;
    }
}

// ---------------- generic fp32 GEMM: C[M,N] = A[M,K] * W^T (+bias +rowbase) ----------------
// BMODE 0: W is [N][ldb]; BMODE 1: W is [K][ldb=N]
// EPI 0: C[r*N+n]; EPI 1: out[(b*256+t)*N+n]; EPI 2: out[(r>>5)*N*32 + n*32 + (r&31)]
// EPI 3: packed-transposed state out[(n>>2)*128 + (r&31)*4 + (n&3)]  (M<=32)
// GATHER 1: A row r = emb_table[dec_in[(r&31)*256 + (r>>5)]]
template<int BMODE, int EPI, int GATHER>
__global__ __launch_bounds__(256, 2)
void gemm128(const float* __restrict__ A, int lda,
             const float* __restrict__ W, int ldb,
             const float* __restrict__ bias,
             const float* __restrict__ rowbase,
             const int*   __restrict__ gidx,
             float* __restrict__ Cout,
             int M, int N, int K)
{
    __shared__ float As[8][132];
    __shared__ float Bs[8][132];
    const int tid = threadIdx.x;
    const int r0 = blockIdx.x * 128;
    const int n0 = blockIdx.y * 128;
    const int tx = tid & 15;
    const int ty = tid >> 4;

    float acc[8][8];
#pragma unroll
    for (int i = 0; i < 8; ++i)
#pragma unroll
        for (int j = 0; j < 8; ++j) acc[i][j] = 0.0f;

    const int am  = tid >> 1;
    const int akq = (tid & 1) * 4;
    const bool avalid = (r0 + am) < M;
    const float* arow;
    {
        int r = r0 + am; if (r >= M) r = M - 1;
        if (GATHER) {
            int idx = gidx[(r & 31) * 256 + (r >> 5)];
            arow = A + (size_t)idx * lda;
        } else {
            arow = A + (size_t)r * lda;
        }
    }

    for (int k0 = 0; k0 < K; k0 += 8) {
        float4 av = make_float4(0.f, 0.f, 0.f, 0.f);
        if (avalid) av = *(const float4*)(arow + k0 + akq);

        if (BMODE == 0) {
            const int ncol = tid >> 1;
            const int kq   = (tid & 1) * 4;
            float4 bv = make_float4(0.f, 0.f, 0.f, 0.f);
            int j = n0 + ncol;
            if (j < N) bv = *(const float4*)(W + (size_t)j * ldb + k0 + kq);
            __syncthreads();
            As[akq + 0][am] = av.x; As[akq + 1][am] = av.y;
            As[akq + 2][am] = av.z; As[akq + 3][am] = av.w;
            Bs[kq + 0][ncol] = bv.x; Bs[kq + 1][ncol] = bv.y;
            Bs[kq + 2][ncol] = bv.z; Bs[kq + 3][ncol] = bv.w;
        } else {
            const int kk = tid >> 5;
            const int nq = (tid & 31) * 4;
            float4 bv = make_float4(0.f, 0.f, 0.f, 0.f);
            int j = n0 + nq;
            if (j < N) bv = *(const float4*)(W + (size_t)(k0 + kk) * ldb + j);
            __syncthreads();
            As[akq + 0][am] = av.x; As[akq + 1][am] = av.y;
            As[akq + 2][am] = av.z; As[akq + 3][am] = av.w;
            *(float4*)&Bs[kk][nq] = bv;
        }
        __syncthreads();

#pragma unroll
        for (int kk = 0; kk < 8; ++kk) {
            float4 a0 = *(const float4*)&As[kk][ty * 8];
            float4 a1 = *(const float4*)&As[kk][ty * 8 + 4];
            float4 b0 = *(const float4*)&Bs[kk][tx * 8];
            float4 b1 = *(const float4*)&Bs[kk][tx * 8 + 4];
            float ar[8] = {a0.x, a0.y, a0.z, a0.w, a1.x, a1.y, a1.z, a1.w};
            float br[8] = {b0.x, b0.y, b0.z, b0.w, b1.x, b1.y, b1.z, b1.w};
#pragma unroll
            for (int i = 0; i < 8; ++i)
#pragma unroll
                for (int j = 0; j < 8; ++j)
                    acc[i][j] = fmaf(ar[i], br[j], acc[i][j]);
        }
    }

#pragma unroll
    for (int i = 0; i < 8; ++i) {
        int r = r0 + ty * 8 + i;
        if (r >= M) continue;
        const float* rb = rowbase ? (rowbase + (size_t)(r & 31) * N) : nullptr;
#pragma unroll
        for (int jq = 0; jq < 2; ++jq) {
            int n = n0 + tx * 8 + jq * 4;
            if (n >= N) continue;
            float4 v;
            v.x = acc[i][jq * 4 + 0]; v.y = acc[i][jq * 4 + 1];
            v.z = acc[i][jq * 4 + 2]; v.w = acc[i][jq * 4 + 3];
            if (bias) {
                float4 bz = *(const float4*)(bias + n);
                v.x += bz.x; v.y += bz.y; v.z += bz.z; v.w += bz.w;
            }
            if (rb) {
                float4 rz = *(const float4*)(rb + n);
                v.x += rz.x; v.y += rz.y; v.z += rz.z; v.w += rz.w;
            }
            if (EPI == 2) {
                size_t basei = (size_t)(r >> 5) * (size_t)N * 32 + (size_t)(r & 31);
                Cout[basei + (size_t)(n + 0) * 32] = v.x;
                Cout[basei + (size_t)(n + 1) * 32] = v.y;
                Cout[basei + (size_t)(n + 2) * 32] = v.z;
                Cout[basei + (size_t)(n + 3) * 32] = v.w;
            } else if (EPI == 3) {
                *(float4*)(Cout + (size_t)(n >> 2) * 128 + (size_t)(r & 31) * 4) = v;
            } else {
                float* crow = (EPI == 0) ? (Cout + (size_t)r * N)
                                         : (Cout + (size_t)((r & 31) * 256 + (r >> 5)) * (size_t)N);
                *(float4*)(crow + n) = v;
            }
        }
    }
}

// ---------------- manual grid barrier, fence-minimal (graph-capturable) ----------------
// Monotonic counter (no reset -> no reset/reorder race). Arrive: RELAXED fetch_add.
// Spin: RELAXED agent loads (NO buffer_inv per poll). Exactly ONE release fence
// (buffer_wbl2) before arrive and ONE acquire fence (buffer_inv) after release.
__device__ __forceinline__ void grid_sync(int* cnt, int target) {
    __syncthreads();
    if (threadIdx.x == 0) {
        __builtin_amdgcn_fence(__ATOMIC_RELEASE, "agent");   // one wbl2: flush block's writes
        __hip_atomic_fetch_add(cnt, 1, __ATOMIC_RELAXED, __HIP_MEMORY_SCOPE_AGENT);
        int spins = 0;
        while (__hip_atomic_load(cnt, __ATOMIC_RELAXED, __HIP_MEMORY_SCOPE_AGENT) < target) {
            __builtin_amdgcn_s_sleep(4);
            if (++spins > (1 << 20)) break;   // safety bail: visible failure, not a hang
        }
        __builtin_amdgcn_fence(__ATOMIC_ACQUIRE, "agent");   // one inv: drop stale lines
    }
    __syncthreads();
}

// ---------------- persistent scan, LDS weights, broadcast reads, regular launch -------------
// 256 blocks x 512 threads (1 block/CU via 157.8KB LDS). Block bk owns u in {4bk..4bk+3}.
// Thread: b = tid&31 (lane), kk = (tid>>5)&1, ks = tid>>6 (wave). k-slice = ks*128 + kk*64.
// State layout (packed transposed): h[(u>>2)][b][u&3]; ring of 2 slots for aT and bT.
// Weight LDS: wlds[(ul*9+v)*1024 + k] — all 64 lanes of a wave read the same float4 (kk gives
// 2 distinct addrs = 2-way broadcast = free).
__global__ __launch_bounds__(512, 2)
void scan_persistent(const float* __restrict__ gi1T,  // [256][3072][32]
                     float* __restrict__ aT,           // [2][256][32][4]
                     float* __restrict__ bT,           // [2][256][32][4]
                     float* __restrict__ bSeq,         // [257][32][1024] (slots 1..256 written)
                     float* __restrict__ gbuf,         // [2][3072][32]
                     const float* __restrict__ Whh1, const float* __restrict__ bhh1,
                     const float* __restrict__ Wih2, const float* __restrict__ bih2,
                     const float* __restrict__ Whh2, const float* __restrict__ bhh2,
                     int* __restrict__ barCnt)
{
    __shared__ float wlds[36864];      // 144 KB
    __shared__ float part[8][9][32];   // 9.2 KB
    __shared__ float gsum[9][32];      // 1.2 KB

    const int tid = threadIdx.x;
    const int b   = tid & 31;
    const int kk  = (tid >> 5) & 1;
    const int ks  = tid >> 6;
    const int bk  = blockIdx.x;
    const int koff = ks * 128 + kk * 64;
    const int role = tid >> 5;         // writers: tid<96 -> roles 0(L1),1(G2),2(L2)

    // ---- stage weights once: v0-2 Whh1, v3-5 Wih2, v6-8 Whh2, for u = 4bk+ul ----
    for (int c = tid; c < 9216; c += 512) {     // c = float4 index
        int k4 = c & 255;
        int uv = c >> 8;                        // 0..35
        int ul = uv / 9, v = uv - ul * 9;
        int u  = bk * 4 + ul;
        const float* W = (v < 3) ? Whh1 : (v < 6 ? Wih2 : Whh2);
        int g = v % 3;
        float4 w = *(const float4*)(W + ((size_t)(g * 1024 + u)) * 1024 + k4 * 4);
        *(float4*)&wlds[(size_t)uv * 1024 + k4 * 4] = w;
    }

    // per-writer bias constants
    float wb[3][4];
    if (tid < 96) {
        const float* bias = (role == 0) ? bhh1 : (role == 1 ? bih2 : bhh2);
#pragma unroll
        for (int g = 0; g < 3; ++g)
#pragma unroll
            for (int ul = 0; ul < 4; ++ul)
                wb[g][ul] = bias[g * 1024 + bk * 4 + ul];
    }
    __syncthreads();

    float aOut[4] = {0, 0, 0, 0};
    float bOut[4] = {0, 0, 0, 0};

    for (int s = 0; s <= 257; ++s) {
        const bool doL1 = (s <= 255);
        const bool doG2 = (s >= 1 && s <= 256);
        const bool doL2 = (s >= 2);
        const bool doA  = doL1 || doG2;
        const int slot  = s & 1;

        // ---- writer-role prefetch (gate inputs + previous h), hidden under compute ----
        float pgi[3][4];
        float4 hprev = make_float4(0.f, 0.f, 0.f, 0.f);
        if (role == 0 && doL1) {
            const float* gi = gi1T + (size_t)s * 98304;
#pragma unroll
            for (int g = 0; g < 3; ++g)
#pragma unroll
                for (int ul = 0; ul < 4; ++ul)
                    pgi[g][ul] = gi[(g * 1024 + bk * 4 + ul) * 32 + b];
            hprev = *((const float4*)aT + (size_t)slot * 8192 + bk * 32 + b);
        } else if (role == 2 && doL2) {
            const float* g2 = gbuf + (size_t)((s + 1) & 1) * 98304;
#pragma unroll
            for (int g = 0; g < 3; ++g)
#pragma unroll
                for (int ul = 0; ul < 4; ++ul)
                    pgi[g][ul] = g2[(g * 1024 + bk * 4 + ul) * 32 + b];
            hprev = *((const float4*)bT + (size_t)slot * 8192 + bk * 32 + b);
        }

        float accA[6][4], accC[3][4];
#pragma unroll
        for (int v = 0; v < 6; ++v)
#pragma unroll
            for (int ul = 0; ul < 4; ++ul) accA[v][ul] = 0.f;
#pragma unroll
        for (int v = 0; v < 3; ++v)
#pragma unroll
            for (int ul = 0; ul < 4; ++ul) accC[v][ul] = 0.f;

        // ---- A-phase: h_a[s] against Whh1 (v0-2) and Wih2 (v3-5) ----
        if (doA) {
            float4 hA[16];
            const float4* src = (const float4*)aT + (size_t)slot * 8192 + b;
#pragma unroll
            for (int i = 0; i < 16; ++i) hA[i] = src[(ks * 32 + kk * 16 + i) * 32];
#pragma unroll
            for (int ul = 0; ul < 4; ++ul)
#pragma unroll
                for (int v = 0; v < 6; ++v) {
                    const float4* w = (const float4*)&wlds[(ul * 9 + v) * 1024 + koff];
                    float s0 = 0.f, s1 = 0.f, s2 = 0.f, s3 = 0.f;
#pragma unroll
                    for (int i = 0; i < 16; ++i) {
                        float4 wv = w[i];
                        s0 = fmaf(hA[i].x, wv.x, s0);
                        s1 = fmaf(hA[i].y, wv.y, s1);
                        s2 = fmaf(hA[i].z, wv.z, s2);
                        s3 = fmaf(hA[i].w, wv.w, s3);
                    }
                    accA[v][ul] = (s0 + s1) + (s2 + s3);
                }
        }
        // ---- C-phase: h_b[s-2] against Whh2 (v6-8) ----
        if (doL2) {
            float4 hB[16];
            const float4* src = (const float4*)bT + (size_t)slot * 8192 + b;
#pragma unroll
            for (int i = 0; i < 16; ++i) hB[i] = src[(ks * 32 + kk * 16 + i) * 32];
#pragma unroll
            for (int ul = 0; ul < 4; ++ul)
#pragma unroll
                for (int v = 0; v < 3; ++v) {
                    const float4* w = (const float4*)&wlds[(ul * 9 + 6 + v) * 1024 + koff];
                    float s0 = 0.f, s1 = 0.f, s2 = 0.f, s3 = 0.f;
#pragma unroll
                    for (int i = 0; i < 16; ++i) {
                        float4 wv = w[i];
                        s0 = fmaf(hB[i].x, wv.x, s0);
                        s1 = fmaf(hB[i].y, wv.y, s1);
                        s2 = fmaf(hB[i].z, wv.z, s2);
                        s3 = fmaf(hB[i].w, wv.w, s3);
                    }
                    accC[v][ul] = (s0 + s1) + (s2 + s3);
                }
        }

        // ---- fold kk (lane bit 5) ----
#pragma unroll
        for (int v = 0; v < 6; ++v)
#pragma unroll
            for (int ul = 0; ul < 4; ++ul)
                accA[v][ul] += __shfl_xor(accA[v][ul], 32);
#pragma unroll
        for (int v = 0; v < 3; ++v)
#pragma unroll
            for (int ul = 0; ul < 4; ++ul)
                accC[v][ul] += __shfl_xor(accC[v][ul], 32);

        // ---- per-u rounds: cross-wave reduce + gates ----
#pragma unroll
        for (int ul = 0; ul < 4; ++ul) {
            if (kk == 0) {
#pragma unroll
                for (int v = 0; v < 6; ++v) part[ks][v][b] = accA[v][ul];
#pragma unroll
                for (int v = 0; v < 3; ++v) part[ks][6 + v][b] = accC[v][ul];
            }
            __syncthreads();
            if (tid < 288) {
                int v = tid >> 5, bb = tid & 31;
                float s8 = 0.f;
#pragma unroll
                for (int r = 0; r < 8; ++r) s8 += part[r][v][bb];
                gsum[v][bb] = s8;
            }
            __syncthreads();
            if (tid < 96) {
                const int u = bk * 4 + ul;
                if (role == 0) {
                    if (doL1) {
                        float r = sigf(pgi[0][ul] + gsum[0][b] + wb[0][ul]);
                        float z = sigf(pgi[1][ul] + gsum[1][b] + wb[1][ul]);
                        float n = tanhf(pgi[2][ul] + r * (gsum[2][b] + wb[2][ul]));
                        float hp = (ul == 0) ? hprev.x : (ul == 1) ? hprev.y : (ul == 2) ? hprev.z : hprev.w;
                        aOut[ul] = (1.0f - z) * n + z * hp;
                    }
                } else if (role == 1) {
                    if (doG2) {
                        float* g2 = gbuf + (size_t)(s & 1) * 98304;
#pragma unroll
                        for (int g = 0; g < 3; ++g)
                            g2[(g * 1024 + u) * 32 + b] = gsum[3 + g][b] + wb[g][ul];
                    }
                } else {
                    if (doL2) {
                        float r = sigf(pgi[0][ul] + gsum[6][b] + wb[0][ul]);
                        float z = sigf(pgi[1][ul] + gsum[7][b] + wb[1][ul]);
                        float n = tanhf(pgi[2][ul] + r * (gsum[8][b] + wb[2][ul]));
                        float hp = (ul == 0) ? hprev.x : (ul == 1) ? hprev.y : (ul == 2) ? hprev.z : hprev.w;
                        bOut[ul] = (1.0f - z) * n + z * hp;
                    }
                }
            }
        }

        // ---- state writes (packed transposed float4; plus bSeq normal layout) ----
        if (role == 0 && doL1) {
            float4 o = make_float4(aOut[0], aOut[1], aOut[2], aOut[3]);
            *((float4*)aT + (size_t)((s + 1) & 1) * 8192 + bk * 32 + b) = o;
        }
        if (role == 2 && doL2) {
            float4 o = make_float4(bOut[0], bOut[1], bOut[2], bOut[3]);
            *((float4*)bT + (size_t)((s + 1) & 1) * 8192 + bk * 32 + b) = o;
            *(float4*)(bSeq + (size_t)(s - 1) * 32768 + (size_t)b * 1024 + bk * 4) = o;
        }

        grid_sync(barCnt, (s + 1) * NBLK);
    }
}

// ---------------- fused log-softmax tail: lse, gather log-prob, argmax ----------------
__global__ __launch_bounds__(256)
void softmax_tail(const float* __restrict__ logits,  // [(b*256+t)][10000]
                  const int*   __restrict__ dec_out,
                  float* __restrict__ lp,
                  float* __restrict__ pred)
{
    const int p = blockIdx.x;
    const int tid = threadIdx.x;
    const float* row = logits + (size_t)p * 10000;

    float m = -INFINITY, s = 0.0f;
    int am = 0;
    for (int q = tid; q < 2500; q += 256) {
        float4 v = *(const float4*)(row + q * 4);
        float xs[4] = {v.x, v.y, v.z, v.w};
#pragma unroll
        for (int c = 0; c < 4; ++c) {
            float x = xs[c];
            if (x > m) {
                s = s * __expf(m - x) + 1.0f;
                m = x;
                am = q * 4 + c;
            } else {
                s += __expf(x - m);
            }
        }
    }
    __shared__ float sm[256];
    __shared__ float ss[256];
    __shared__ int   sa[256];
    sm[tid] = m; ss[tid] = s; sa[tid] = am;
    __syncthreads();
    for (int w = 128; w > 0; w >>= 1) {
        if (tid < w) {
            float m1 = sm[tid],     s1 = ss[tid];     int a1 = sa[tid];
            float m2 = sm[tid + w], s2 = ss[tid + w]; int a2 = sa[tid + w];
            float M2 = fmaxf(m1, m2);
            float S2 = s1 * __expf(m1 - M2) + s2 * __expf(m2 - M2);
            int A2;
            if (m1 > m2) A2 = a1;
            else if (m2 > m1) A2 = a2;
            else A2 = (a1 < a2) ? a1 : a2;
            sm[tid] = M2; ss[tid] = S2; sa[tid] = A2;
        }
        __syncthreads();
    }
    if (tid == 0) {
        float lse = sm[0] + logf(ss[0]);
        int tok = dec_out[p];
        lp[p]   = row[tok] - lse;
        pred[p] = (float)sa[0];
    }
}

extern "C" void kernel_launch(void* const* d_in, const int* in_sizes, int n_in,
                              void* d_out, int out_size, void* d_ws, size_t ws_size,
                              hipStream_t stream)
{
    const float* enc_output  = (const float*)d_in[0];
    const int*   enc_len     = (const int*)  d_in[1];
    const int*   styles      = (const int*)  d_in[2];
    const int*   dec_in      = (const int*)  d_in[3];
    const int*   dec_out     = (const int*)  d_in[4];
    const float* emb_table   = (const float*)d_in[5];
    const float* style_table = (const float*)d_in[6];
    const float* Wp   = (const float*)d_in[7];
    const float* bp   = (const float*)d_in[8];
    const float* Wih1 = (const float*)d_in[9];
    const float* Whh1 = (const float*)d_in[10];
    const float* bih1 = (const float*)d_in[11];
    const float* bhh1 = (const float*)d_in[12];
    const float* Wih2 = (const float*)d_in[13];
    const float* Whh2 = (const float*)d_in[14];
    const float* bih2 = (const float*)d_in[15];
    const float* bhh2 = (const float*)d_in[16];
    const float* Wout = (const float*)d_in[17];
    const float* bout = (const float*)d_in[18];

    float* out = (float*)d_out;

    // Scratch inside the logits region of d_out (all dead before logits GEMM overwrites):
    float* gi1T  = out;                  // [256][3072][32]   = 25,165,824 f
    float* aT    = out + 25165824;       // [2][256][32][4]   =     65,536 f
    float* bTr   = out + 25231360;       // [2][256][32][4]   =     65,536 f
    float* base1 = out + 25296896;       // [32][3072]        =     98,304 f
    float* xA    = out + 25395200;       // [32][1032]
    float* xB    = out + 25428224;       // [32][1032]
    float* gbuf  = out + 25461248;       // [2][3072][32]     =    196,608 f
    int*   barP  = (int*)(out + 25657856); // counter (+pad)  (ends far below 81,920,000)
    // b_seq (normal layout, feeds logits GEMM) survives into the GEMM -> d_ws:
    float* bSeq  = (float*)d_ws;         // [257][32][1024] = 33.7 MB

    float* logitsOut = out;              // [32][256][10000]
    float* lpOut     = out + 81920000;   // [32][256]
    float* predOut   = out + 81928192;   // [32][256]

    // Phase 0: gather + concat vectors + zero bT slot 0
    prep_kernel<<<32, 256, 0, stream>>>(enc_output, enc_len, styles, style_table, xA, xB, bTr);

    // h0 = xA @ Wp^T + bp -> aT slot 0 (packed transposed via EPI 3)
    gemm128<0, 3, 0><<<dim3(1, 8), 256, 0, stream>>>(xA, 1032, Wp, 1032, bp, nullptr, nullptr,
                                                     aT, 32, 1024, 1032);
    // base1 = xB @ Wih1[:, 512:]^T + bih1
    gemm128<0, 0, 0><<<dim3(1, 24), 256, 0, stream>>>(xB, 1032, Wih1 + 512, 1544, bih1, nullptr, nullptr,
                                                      base1, 32, 3072, 1032);
    // gi1T[t][col][b] = (emb[dec_in] @ Wih1[:, :512]^T + base1[b]) transposed per t
    gemm128<0, 2, 1><<<dim3(64, 24), 256, 0, stream>>>(emb_table, 512, Wih1, 1544, nullptr, base1, dec_in,
                                                       gi1T, 8192, 3072, 512);

    // barrier counter must start at 0 every call (out is poisoned, not re-zeroed)
    hipMemsetAsync(barP, 0, 256, stream);

    // Persistent pipelined scan: regular launch (graph-capturable), fence-minimal barrier
    scan_persistent<<<NBLK, 512, 0, stream>>>(gi1T, aT, bTr, bSeq, gbuf,
                                              Whh1, bhh1, Wih2, bih2, Whh2, bhh2,
                                              barP);

    // logits = b_seq[1..256] @ Wout + bout, written in [b][t][v] order
    gemm128<1, 1, 0><<<dim3(64, 79), 256, 0, stream>>>(bSeq + 32768, 1024, Wout, 10000, bout, nullptr, nullptr,
                                                       logitsOut, 8192, 10000, 1024);
    // log-softmax gather + argmax
    softmax_tail<<<8192, 256, 0, stream>>>(logitsOut, dec_out, lpOut, predOut);
}

// Round 8
// 9292.702 us; speedup vs baseline: 2.3007x; 1.5991x over previous
//
#include <hip/hip_runtime.h>
#include <math.h>

// Sizes: B=32, S=256, T=256, V=10000, E=512, H=1024, C=1024, SE=8
// in1 = E+SE+C = 1544, 3H = 3072, M = B*T = 8192 (row r = t*32 + b)
#define NBLK 256
#define GROUPS 16
#define GSIZE 16

__device__ __forceinline__ float sigf(float x) { return 1.0f / (1.0f + __expf(-x)); }

// ---------------- prep: gather ctx/style, build concat vectors, zero bT slot 0 --------------
__global__ void prep_kernel(const float* __restrict__ enc_output,
                            const int*   __restrict__ enc_len,
                            const int*   __restrict__ styles,
                            const float* __restrict__ style_table,
                            float* __restrict__ xA,     // [32][1032] = [ctx, style]
                            float* __restrict__ xB,     // [32][1032] = [style, ctx]
                            float* __restrict__ bT0)    // [256][32][4] zeros (b_state[0], packed)
{
    int b = blockIdx.x;
    int tid = threadIdx.x;
    int last = enc_len[b] - 1;
    last = last < 0 ? 0 : (last > 255 ? 255 : last);
    const float* ctx = enc_output + ((size_t)b * 256 + last) * 1024;
    for (int k = tid; k < 1024; k += blockDim.x) {
        float v = ctx[k];
        xA[b * 1032 + k]     = v;
        xB[b * 1032 + 8 + k] = v;
        bT0[b * 1024 + k]    = 0.0f;   // 32 blocks x 1024 = 32768 floats
    }
    if (tid < 8) {
        float se = style_table[styles[b] * 8 + tid];
        xA[b * 1032 + 1024 + tid] = se;
        xB[b * 1032 + tid]        = se;
    }
}

// ---------------- generic fp32 GEMM: C[M,N] = A[M,K] * W^T (+bias +rowbase) ----------------
// BMODE 0: W is [N][ldb]; BMODE 1: W is [K][ldb=N]
// EPI 0: C[r*N+n]; EPI 1: out[(b*256+t)*N+n]; EPI 2: out[(r>>5)*N*32 + n*32 + (r&31)]
// EPI 3: packed-transposed state out[(n>>2)*128 + (r&31)*4 + (n&3)]  (M<=32)
// GATHER 1: A row r = emb_table[dec_in[(r&31)*256 + (r>>5)]]
template<int BMODE, int EPI, int GATHER>
__global__ __launch_bounds__(256, 2)
void gemm128(const float* __restrict__ A, int lda,
             const float* __restrict__ W, int ldb,
             const float* __restrict__ bias,
             const float* __restrict__ rowbase,
             const int*   __restrict__ gidx,
             float* __restrict__ Cout,
             int M, int N, int K)
{
    __shared__ float As[8][132];
    __shared__ float Bs[8][132];
    const int tid = threadIdx.x;
    const int r0 = blockIdx.x * 128;
    const int n0 = blockIdx.y * 128;
    const int tx = tid & 15;
    const int ty = tid >> 4;

    float acc[8][8];
#pragma unroll
    for (int i = 0; i < 8; ++i)
#pragma unroll
        for (int j = 0; j < 8; ++j) acc[i][j] = 0.0f;

    const int am  = tid >> 1;
    const int akq = (tid & 1) * 4;
    const bool avalid = (r0 + am) < M;
    const float* arow;
    {
        int r = r0 + am; if (r >= M) r = M - 1;
        if (GATHER) {
            int idx = gidx[(r & 31) * 256 + (r >> 5)];
            arow = A + (size_t)idx * lda;
        } else {
            arow = A + (size_t)r * lda;
        }
    }

    for (int k0 = 0; k0 < K; k0 += 8) {
        float4 av = make_float4(0.f, 0.f, 0.f, 0.f);
        if (avalid) av = *(const float4*)(arow + k0 + akq);

        if (BMODE == 0) {
            const int ncol = tid >> 1;
            const int kq   = (tid & 1) * 4;
            float4 bv = make_float4(0.f, 0.f, 0.f, 0.f);
            int j = n0 + ncol;
            if (j < N) bv = *(const float4*)(W + (size_t)j * ldb + k0 + kq);
            __syncthreads();
            As[akq + 0][am] = av.x; As[akq + 1][am] = av.y;
            As[akq + 2][am] = av.z; As[akq + 3][am] = av.w;
            Bs[kq + 0][ncol] = bv.x; Bs[kq + 1][ncol] = bv.y;
            Bs[kq + 2][ncol] = bv.z; Bs[kq + 3][ncol] = bv.w;
        } else {
            const int kk = tid >> 5;
            const int nq = (tid & 31) * 4;
            float4 bv = make_float4(0.f, 0.f, 0.f, 0.f);
            int j = n0 + nq;
            if (j < N) bv = *(const float4*)(W + (size_t)(k0 + kk) * ldb + j);
            __syncthreads();
            As[akq + 0][am] = av.x; As[akq + 1][am] = av.y;
            As[akq + 2][am] = av.z; As[akq + 3][am] = av.w;
            *(float4*)&Bs[kk][nq] = bv;
        }
        __syncthreads();

#pragma unroll
        for (int kk = 0; kk < 8; ++kk) {
            float4 a0 = *(const float4*)&As[kk][ty * 8];
            float4 a1 = *(const float4*)&As[kk][ty * 8 + 4];
            float4 b0 = *(const float4*)&Bs[kk][tx * 8];
            float4 b1 = *(const float4*)&Bs[kk][tx * 8 + 4];
            float ar[8] = {a0.x, a0.y, a0.z, a0.w, a1.x, a1.y, a1.z, a1.w};
            float br[8] = {b0.x, b0.y, b0.z, b0.w, b1.x, b1.y, b1.z, b1.w};
#pragma unroll
            for (int i = 0; i < 8; ++i)
#pragma unroll
                for (int j = 0; j < 8; ++j)
                    acc[i][j] = fmaf(ar[i], br[j], acc[i][j]);
        }
    }

#pragma unroll
    for (int i = 0; i < 8; ++i) {
        int r = r0 + ty * 8 + i;
        if (r >= M) continue;
        const float* rb = rowbase ? (rowbase + (size_t)(r & 31) * N) : nullptr;
#pragma unroll
        for (int jq = 0; jq < 2; ++jq) {
            int n = n0 + tx * 8 + jq * 4;
            if (n >= N) continue;
            float4 v;
            v.x = acc[i][jq * 4 + 0]; v.y = acc[i][jq * 4 + 1];
            v.z = acc[i][jq * 4 + 2]; v.w = acc[i][jq * 4 + 3];
            if (bias) {
                float4 bz = *(const float4*)(bias + n);
                v.x += bz.x; v.y += bz.y; v.z += bz.z; v.w += bz.w;
            }
            if (rb) {
                float4 rz = *(const float4*)(rb + n);
                v.x += rz.x; v.y += rz.y; v.z += rz.z; v.w += rz.w;
            }
            if (EPI == 2) {
                size_t basei = (size_t)(r >> 5) * (size_t)N * 32 + (size_t)(r & 31);
                Cout[basei + (size_t)(n + 0) * 32] = v.x;
                Cout[basei + (size_t)(n + 1) * 32] = v.y;
                Cout[basei + (size_t)(n + 2) * 32] = v.z;
                Cout[basei + (size_t)(n + 3) * 32] = v.w;
            } else if (EPI == 3) {
                *(float4*)(Cout + (size_t)(n >> 2) * 128 + (size_t)(r & 31) * 4) = v;
            } else {
                float* crow = (EPI == 0) ? (Cout + (size_t)r * N)
                                         : (Cout + (size_t)((r & 31) * 256 + (r >> 5)) * (size_t)N);
                *(float4*)(crow + n) = v;
            }
        }
    }
}

// ---------------- coherent (L3-point) access helpers: no wbl2/inv anywhere ----------------
__device__ __forceinline__ float4 coh_load4(const float4* p) {
    const unsigned long long* q = (const unsigned long long*)p;
    union { float4 f; unsigned long long u[2]; } cv;
    cv.u[0] = __hip_atomic_load((unsigned long long*)q,     __ATOMIC_RELAXED, __HIP_MEMORY_SCOPE_AGENT);
    cv.u[1] = __hip_atomic_load((unsigned long long*)q + 1, __ATOMIC_RELAXED, __HIP_MEMORY_SCOPE_AGENT);
    return cv.f;
}
__device__ __forceinline__ void coh_store4(float4* p, float4 v) {
    unsigned long long* q = (unsigned long long*)p;
    union { float4 f; unsigned long long u[2]; } cv; cv.f = v;
    __hip_atomic_store(q,     cv.u[0], __ATOMIC_RELAXED, __HIP_MEMORY_SCOPE_AGENT);
    __hip_atomic_store(q + 1, cv.u[1], __ATOMIC_RELAXED, __HIP_MEMORY_SCOPE_AGENT);
}

// ---------------- fence-free hierarchical grid barrier (graph-capturable) ----------------
// Monotonic counters, no resets. 16 groups x 16 blocks; per-group arrive counter and go-word
// on separate 256B lines. Global-last block fans out go=epoch to all 16 group lines.
// Ordering: hipcc drains vmcnt(0) before s_barrier, so every block's sc1 state-stores are at
// the L3 coherence point before its arrive-RMW; RMW return-value dependencies chain all 256
// blocks' arrivals before the go store. Pollers use relaxed sc1 loads (no cache invalidate).
__device__ __forceinline__ void grid_sync(int* bar, int epoch, int grp) {
    __syncthreads();
    if (threadIdx.x == 0) {
        int prev = __hip_atomic_fetch_add(bar + grp * 64, 1, __ATOMIC_RELAXED, __HIP_MEMORY_SCOPE_AGENT);
        if (prev == epoch * GSIZE - 1) {
            int rprev = __hip_atomic_fetch_add(bar + 1024, 1, __ATOMIC_RELAXED, __HIP_MEMORY_SCOPE_AGENT);
            if (rprev == epoch * GROUPS - 1) {
#pragma unroll
                for (int j = 0; j < GROUPS; ++j)
                    __hip_atomic_store(bar + 1088 + j * 64, epoch, __ATOMIC_RELAXED, __HIP_MEMORY_SCOPE_AGENT);
            }
        }
        int spins = 0;
        while (__hip_atomic_load(bar + 1088 + grp * 64, __ATOMIC_RELAXED, __HIP_MEMORY_SCOPE_AGENT) < epoch) {
            __builtin_amdgcn_s_sleep(8);
            if (++spins > (1 << 20)) break;   // safety bail: visible failure, not a hang
        }
    }
    __syncthreads();
}

// ---------------- persistent scan, LDS weights, coherent state, fence-free barrier ----------
// 256 blocks x 512 threads (1 block/CU via 157.8KB LDS). Block bk owns u in {4bk..4bk+3}.
// Thread: b = tid&31 (lane), kk = (tid>>5)&1, ks = tid>>6 (wave). k-slice = ks*128 + kk*64.
// State (packed transposed) h[(u>>2)][b][u&3], 2-slot ring; accessed ONLY via sc1 atomics.
// gbuf is block-local (regular cached ops); gi1T read-only stream (regular, stays cached).
__global__ __launch_bounds__(512, 2)
void scan_persistent(const float* __restrict__ gi1T,  // [256][3072][32]
                     float* __restrict__ aT,           // [2][256][32][4]
                     float* __restrict__ bT,           // [2][256][32][4]
                     float* __restrict__ bSeq,         // [257][32][1024] (slots 1..256 written)
                     float* __restrict__ gbuf,         // [2][3072][32]
                     const float* __restrict__ Whh1, const float* __restrict__ bhh1,
                     const float* __restrict__ Wih2, const float* __restrict__ bih2,
                     const float* __restrict__ Whh2, const float* __restrict__ bhh2,
                     int* __restrict__ barP)
{
    __shared__ float wlds[36864];      // 144 KB
    __shared__ float part[8][9][32];   // 9.2 KB
    __shared__ float gsum[9][32];      // 1.2 KB

    const int tid = threadIdx.x;
    const int b   = tid & 31;
    const int kk  = (tid >> 5) & 1;
    const int ks  = tid >> 6;
    const int bk  = blockIdx.x;
    const int grp = bk >> 4;
    const int koff = ks * 128 + kk * 64;
    const int role = tid >> 5;         // writers: tid<96 -> roles 0(L1),1(G2),2(L2)

    // ---- stage weights once: v0-2 Whh1, v3-5 Wih2, v6-8 Whh2, for u = 4bk+ul ----
    for (int c = tid; c < 9216; c += 512) {     // c = float4 index
        int k4 = c & 255;
        int uv = c >> 8;                        // 0..35
        int ul = uv / 9, v = uv - ul * 9;
        int u  = bk * 4 + ul;
        const float* W = (v < 3) ? Whh1 : (v < 6 ? Wih2 : Whh2);
        int g = v % 3;
        float4 w = *(const float4*)(W + ((size_t)(g * 1024 + u)) * 1024 + k4 * 4);
        *(float4*)&wlds[(size_t)uv * 1024 + k4 * 4] = w;
    }

    // per-writer bias constants
    float wb[3][4];
    if (tid < 96) {
        const float* bias = (role == 0) ? bhh1 : (role == 1 ? bih2 : bhh2);
#pragma unroll
        for (int g = 0; g < 3; ++g)
#pragma unroll
            for (int ul = 0; ul < 4; ++ul)
                wb[g][ul] = bias[g * 1024 + bk * 4 + ul];
    }
    __syncthreads();

    float aOut[4] = {0, 0, 0, 0};
    float bOut[4] = {0, 0, 0, 0};

    for (int s = 0; s <= 257; ++s) {
        const bool doL1 = (s <= 255);
        const bool doG2 = (s >= 1 && s <= 256);
        const bool doL2 = (s >= 2);
        const bool doA  = doL1 || doG2;
        const int slot  = s & 1;

        // ---- writer-role prefetch (gate inputs + previous h), hidden under compute ----
        float pgi[3][4];
        float4 hprev = make_float4(0.f, 0.f, 0.f, 0.f);
        if (role == 0 && doL1) {
            const float* gi = gi1T + (size_t)s * 98304;
#pragma unroll
            for (int g = 0; g < 3; ++g)
#pragma unroll
                for (int ul = 0; ul < 4; ++ul)
                    pgi[g][ul] = gi[(g * 1024 + bk * 4 + ul) * 32 + b];
            hprev = coh_load4((const float4*)aT + (size_t)slot * 8192 + bk * 32 + b);
        } else if (role == 2 && doL2) {
            const float* g2 = gbuf + (size_t)((s + 1) & 1) * 98304;
#pragma unroll
            for (int g = 0; g < 3; ++g)
#pragma unroll
                for (int ul = 0; ul < 4; ++ul)
                    pgi[g][ul] = g2[(g * 1024 + bk * 4 + ul) * 32 + b];
            hprev = coh_load4((const float4*)bT + (size_t)slot * 8192 + bk * 32 + b);
        }

        float accA[6][4], accC[3][4];
#pragma unroll
        for (int v = 0; v < 6; ++v)
#pragma unroll
            for (int ul = 0; ul < 4; ++ul) accA[v][ul] = 0.f;
#pragma unroll
        for (int v = 0; v < 3; ++v)
#pragma unroll
            for (int ul = 0; ul < 4; ++ul) accC[v][ul] = 0.f;

        // ---- A-phase: h_a[s] against Whh1 (v0-2) and Wih2 (v3-5) ----
        if (doA) {
            float4 hA[16];
            const float4* src = (const float4*)aT + (size_t)slot * 8192 + b;
#pragma unroll
            for (int i = 0; i < 16; ++i) hA[i] = coh_load4(src + (size_t)((ks * 32 + kk * 16 + i) * 32));
#pragma unroll
            for (int ul = 0; ul < 4; ++ul)
#pragma unroll
                for (int v = 0; v < 6; ++v) {
                    const float4* w = (const float4*)&wlds[(ul * 9 + v) * 1024 + koff];
                    float s0 = 0.f, s1 = 0.f, s2 = 0.f, s3 = 0.f;
#pragma unroll
                    for (int i = 0; i < 16; ++i) {
                        float4 wv = w[i];
                        s0 = fmaf(hA[i].x, wv.x, s0);
                        s1 = fmaf(hA[i].y, wv.y, s1);
                        s2 = fmaf(hA[i].z, wv.z, s2);
                        s3 = fmaf(hA[i].w, wv.w, s3);
                    }
                    accA[v][ul] = (s0 + s1) + (s2 + s3);
                }
        }
        // ---- C-phase: h_b[s-2] against Whh2 (v6-8) ----
        if (doL2) {
            float4 hB[16];
            const float4* src = (const float4*)bT + (size_t)slot * 8192 + b;
#pragma unroll
            for (int i = 0; i < 16; ++i) hB[i] = coh_load4(src + (size_t)((ks * 32 + kk * 16 + i) * 32));
#pragma unroll
            for (int ul = 0; ul < 4; ++ul)
#pragma unroll
                for (int v = 0; v < 3; ++v) {
                    const float4* w = (const float4*)&wlds[(ul * 9 + 6 + v) * 1024 + koff];
                    float s0 = 0.f, s1 = 0.f, s2 = 0.f, s3 = 0.f;
#pragma unroll
                    for (int i = 0; i < 16; ++i) {
                        float4 wv = w[i];
                        s0 = fmaf(hB[i].x, wv.x, s0);
                        s1 = fmaf(hB[i].y, wv.y, s1);
                        s2 = fmaf(hB[i].z, wv.z, s2);
                        s3 = fmaf(hB[i].w, wv.w, s3);
                    }
                    accC[v][ul] = (s0 + s1) + (s2 + s3);
                }
        }

        // ---- fold kk (lane bit 5) ----
#pragma unroll
        for (int v = 0; v < 6; ++v)
#pragma unroll
            for (int ul = 0; ul < 4; ++ul)
                accA[v][ul] += __shfl_xor(accA[v][ul], 32);
#pragma unroll
        for (int v = 0; v < 3; ++v)
#pragma unroll
            for (int ul = 0; ul < 4; ++ul)
                accC[v][ul] += __shfl_xor(accC[v][ul], 32);

        // ---- per-u rounds: cross-wave reduce + gates ----
#pragma unroll
        for (int ul = 0; ul < 4; ++ul) {
            if (kk == 0) {
#pragma unroll
                for (int v = 0; v < 6; ++v) part[ks][v][b] = accA[v][ul];
#pragma unroll
                for (int v = 0; v < 3; ++v) part[ks][6 + v][b] = accC[v][ul];
            }
            __syncthreads();
            if (tid < 288) {
                int v = tid >> 5, bb = tid & 31;
                float s8 = 0.f;
#pragma unroll
                for (int r = 0; r < 8; ++r) s8 += part[r][v][bb];
                gsum[v][bb] = s8;
            }
            __syncthreads();
            if (tid < 96) {
                const int u = bk * 4 + ul;
                if (role == 0) {
                    if (doL1) {
                        float r = sigf(pgi[0][ul] + gsum[0][b] + wb[0][ul]);
                        float z = sigf(pgi[1][ul] + gsum[1][b] + wb[1][ul]);
                        float n = tanhf(pgi[2][ul] + r * (gsum[2][b] + wb[2][ul]));
                        float hp = (ul == 0) ? hprev.x : (ul == 1) ? hprev.y : (ul == 2) ? hprev.z : hprev.w;
                        aOut[ul] = (1.0f - z) * n + z * hp;
                    }
                } else if (role == 1) {
                    if (doG2) {
                        float* g2 = gbuf + (size_t)(s & 1) * 98304;
#pragma unroll
                        for (int g = 0; g < 3; ++g)
                            g2[(g * 1024 + u) * 32 + b] = gsum[3 + g][b] + wb[g][ul];
                    }
                } else {
                    if (doL2) {
                        float r = sigf(pgi[0][ul] + gsum[6][b] + wb[0][ul]);
                        float z = sigf(pgi[1][ul] + gsum[7][b] + wb[1][ul]);
                        float n = tanhf(pgi[2][ul] + r * (gsum[8][b] + wb[2][ul]));
                        float hp = (ul == 0) ? hprev.x : (ul == 1) ? hprev.y : (ul == 2) ? hprev.z : hprev.w;
                        bOut[ul] = (1.0f - z) * n + z * hp;
                    }
                }
            }
        }

        // ---- state writes: coherent sc1 stores for cross-block state; regular for bSeq ----
        if (role == 0 && doL1) {
            float4 o = make_float4(aOut[0], aOut[1], aOut[2], aOut[3]);
            coh_store4((float4*)aT + (size_t)((s + 1) & 1) * 8192 + bk * 32 + b, o);
        }
        if (role == 2 && doL2) {
            float4 o = make_float4(bOut[0], bOut[1], bOut[2], bOut[3]);
            coh_store4((float4*)bT + (size_t)((s + 1) & 1) * 8192 + bk * 32 + b, o);
            *(float4*)(bSeq + (size_t)(s - 1) * 32768 + (size_t)b * 1024 + bk * 4) = o;
        }

        grid_sync(barP, s + 1, grp);
    }
}

// ---------------- fused log-softmax tail: lse, gather log-prob, argmax ----------------
__global__ __launch_bounds__(256)
void softmax_tail(const float* __restrict__ logits,  // [(b*256+t)][10000]
                  const int*   __restrict__ dec_out,
                  float* __restrict__ lp,
                  float* __restrict__ pred)
{
    const int p = blockIdx.x;
    const int tid = threadIdx.x;
    const float* row = logits + (size_t)p * 10000;

    float m = -INFINITY, s = 0.0f;
    int am = 0;
    for (int q = tid; q < 2500; q += 256) {
        float4 v = *(const float4*)(row + q * 4);
        float xs[4] = {v.x, v.y, v.z, v.w};
#pragma unroll
        for (int c = 0; c < 4; ++c) {
            float x = xs[c];
            if (x > m) {
                s = s * __expf(m - x) + 1.0f;
                m = x;
                am = q * 4 + c;
            } else {
                s += __expf(x - m);
            }
        }
    }
    __shared__ float sm[256];
    __shared__ float ss[256];
    __shared__ int   sa[256];
    sm[tid] = m; ss[tid] = s; sa[tid] = am;
    __syncthreads();
    for (int w = 128; w > 0; w >>= 1) {
        if (tid < w) {
            float m1 = sm[tid],     s1 = ss[tid];     int a1 = sa[tid];
            float m2 = sm[tid + w], s2 = ss[tid + w]; int a2 = sa[tid + w];
            float M2 = fmaxf(m1, m2);
            float S2 = s1 * __expf(m1 - M2) + s2 * __expf(m2 - M2);
            int A2;
            if (m1 > m2) A2 = a1;
            else if (m2 > m1) A2 = a2;
            else A2 = (a1 < a2) ? a1 : a2;
            sm[tid] = M2; ss[tid] = S2; sa[tid] = A2;
        }
        __syncthreads();
    }
    if (tid == 0) {
        float lse = sm[0] + logf(ss[0]);
        int tok = dec_out[p];
        lp[p]   = row[tok] - lse;
        pred[p] = (float)sa[0];
    }
}

extern "C" void kernel_launch(void* const* d_in, const int* in_sizes, int n_in,
                              void* d_out, int out_size, void* d_ws, size_t ws_size,
                              hipStream_t stream)
{
    const float* enc_output  = (const float*)d_in[0];
    const int*   enc_len     = (const int*)  d_in[1];
    const int*   styles      = (const int*)  d_in[2];
    const int*   dec_in      = (const int*)  d_in[3];
    const int*   dec_out     = (const int*)  d_in[4];
    const float* emb_table   = (const float*)d_in[5];
    const float* style_table = (const float*)d_in[6];
    const float* Wp   = (const float*)d_in[7];
    const float* bp   = (const float*)d_in[8];
    const float* Wih1 = (const float*)d_in[9];
    const float* Whh1 = (const float*)d_in[10];
    const float* bih1 = (const float*)d_in[11];
    const float* bhh1 = (const float*)d_in[12];
    const float* Wih2 = (const float*)d_in[13];
    const float* Whh2 = (const float*)d_in[14];
    const float* bih2 = (const float*)d_in[15];
    const float* bhh2 = (const float*)d_in[16];
    const float* Wout = (const float*)d_in[17];
    const float* bout = (const float*)d_in[18];

    float* out = (float*)d_out;

    // Scratch inside the logits region of d_out (all dead before logits GEMM overwrites):
    float* gi1T  = out;                  // [256][3072][32]   = 25,165,824 f
    float* aT    = out + 25165824;       // [2][256][32][4]   =     65,536 f
    float* bTr   = out + 25231360;       // [2][256][32][4]   =     65,536 f
    float* base1 = out + 25296896;       // [32][3072]        =     98,304 f
    float* xA    = out + 25395200;       // [32][1032]
    float* xB    = out + 25428224;       // [32][1032]
    float* gbuf  = out + 25461248;       // [2][3072][32]     =    196,608 f
    int*   barP  = (int*)(out + 25657856); // barrier lines (8.4 KB; ends far below 81,920,000)
    // b_seq (normal layout, feeds logits GEMM) survives into the GEMM -> d_ws:
    float* bSeq  = (float*)d_ws;         // [257][32][1024] = 33.7 MB

    float* logitsOut = out;              // [32][256][10000]
    float* lpOut     = out + 81920000;   // [32][256]
    float* predOut   = out + 81928192;   // [32][256]

    // Phase 0: gather + concat vectors + zero bT slot 0
    prep_kernel<<<32, 256, 0, stream>>>(enc_output, enc_len, styles, style_table, xA, xB, bTr);

    // h0 = xA @ Wp^T + bp -> aT slot 0 (packed transposed via EPI 3)
    gemm128<0, 3, 0><<<dim3(1, 8), 256, 0, stream>>>(xA, 1032, Wp, 1032, bp, nullptr, nullptr,
                                                     aT, 32, 1024, 1032);
    // base1 = xB @ Wih1[:, 512:]^T + bih1
    gemm128<0, 0, 0><<<dim3(1, 24), 256, 0, stream>>>(xB, 1032, Wih1 + 512, 1544, bih1, nullptr, nullptr,
                                                      base1, 32, 3072, 1032);
    // gi1T[t][col][b] = (emb[dec_in] @ Wih1[:, :512]^T + base1[b]) transposed per t
    gemm128<0, 2, 1><<<dim3(64, 24), 256, 0, stream>>>(emb_table, 512, Wih1, 1544, nullptr, base1, dec_in,
                                                       gi1T, 8192, 3072, 512);

    // barrier lines must start at 0 every call (out is poisoned, not re-zeroed)
    hipMemsetAsync(barP, 0, 8448, stream);

    // Persistent pipelined scan: regular launch, fence-free hierarchical barrier
    scan_persistent<<<NBLK, 512, 0, stream>>>(gi1T, aT, bTr, bSeq, gbuf,
                                              Whh1, bhh1, Wih2, bih2, Whh2, bhh2,
                                              barP);

    // logits = b_seq[1..256] @ Wout + bout, written in [b][t][v] order
    gemm128<1, 1, 0><<<dim3(64, 79), 256, 0, stream>>>(bSeq + 32768, 1024, Wout, 10000, bout, nullptr, nullptr,
                                                       logitsOut, 8192, 10000, 1024);
    // log-softmax gather + argmax
    softmax_tail<<<8192, 256, 0, stream>>>(logitsOut, dec_out, lpOut, predOut);
}